// Round 10
// baseline (299.593 us; speedup 1.0000x reference)
//
#include <hip/hip_runtime.h>
#include <cstdint>
#include <cstddef>

// EncoderLayer: x(4,2048,1024) f32.
//   prep (1 kernel): W* (KxN f32) -> W*T (NxK bf16); x -> xb bf16
//   G1: qkv_b  = xb @ WqkvT + bqkv              (8192x3072, bf16)  grid 384
//   attn: per-position 16x16 head attention, out (N,H,S,hd) = scrambled reshape
//   G2: ao = aob @ WoT + bo      SPLIT-K=2 -> 2x bf16 partials      grid 256
//   LN1: h_b = LN(p1 + p2 + x)  (bf16 only)
//   G3: ff1 = relu(h_b @ W1T + bf1)             (8192x4096, bf16)  grid 512
//   G4: ff2 = ff1 @ W2T + bf2    SPLIT-K=2 -> 2x bf16 partials      grid 256
//   LN2: out = LN(q1 + q2 + h_b)                (f32 -> d_out)
//
// GEMM v8 "2-phase chunk-pipelined" (R9 postmortem: 4-phase structure
// serializes DS+MFMA because each phase's reads feed only its own MFMA).
// Per K-tile: TWO phases, 4 barriers. Phase A issues all 16 ds_read_b128
// chunk-ordered [A0k0(4) B0k0(2) A0k1(4) B0k1(2) B1k0(2) B1k1(2)] and runs
// 4x8-MFMA chunks (Q00k0,Q00k1,Q01k0,Q01k1) separated by sched_barrier(0):
// the compiler's dep-driven COUNTED lgkmcnt (m97 evidence) then overlaps
// LDS delivery of later chunks with earlier chunks' MFMA. Phase B: A1 reads
// [k0(4) k1(4)], chunks Q11k0,Q10k0,Q11k1,Q10k1. bH/bC (B0/B1 frags) are
// loaded once in phase A and held through phase B (64 frag regs total, no
// shadow sets -> no spill). Staging: phA(t) stages A1,B1(t+1)->buf^1;
// phB(t) stages A0,B0(t+2)->buf; ONE vmcnt(4) per K-tile at end of phB
// (ledger: drains phA(t)'s issues; covers phA(t+1) reads of B1(t+1) and
// phB(t+1) read of A1(t+1) transitively; stages land >=1 barrier after
// their slot's last read).

using f32x4  = __attribute__((ext_vector_type(4))) float;
using bf16x8 = __attribute__((ext_vector_type(8))) __bf16;

__device__ __forceinline__ unsigned short f2b(float f) {
  union { float f; uint32_t u; } v; v.f = f;
  uint32_t r = v.u + 0x7FFFu + ((v.u >> 16) & 1u);  // RNE
  return (unsigned short)(r >> 16);
}
__device__ __forceinline__ float b2f(unsigned short u) {
  union { uint32_t u; float f; } v; v.u = ((uint32_t)u) << 16;
  return v.f;
}

__device__ __forceinline__ void gload_lds16(const unsigned short* g,
                                            unsigned short* l) {
  __builtin_amdgcn_global_load_lds(
      (const __attribute__((address_space(1))) unsigned int*)g,
      (__attribute__((address_space(3))) unsigned int*)l, 16, 0, 0);
}

__device__ __forceinline__ void barrier_sync() {
  __builtin_amdgcn_sched_barrier(0);
  __builtin_amdgcn_s_barrier();
  __builtin_amdgcn_sched_barrier(0);
}
template <int N>
__device__ __forceinline__ void vmwait() {
  __builtin_amdgcn_sched_barrier(0);
  if constexpr (N == 0) asm volatile("s_waitcnt vmcnt(0)");
  if constexpr (N == 4) asm volatile("s_waitcnt vmcnt(4)");
  __builtin_amdgcn_sched_barrier(0);
}

// ---------------- fused prep: 4 weight transposes + x cvt --------------------
__global__ __launch_bounds__(256) void prep_kernel(
    const float* __restrict__ Wqkv, unsigned short* __restrict__ WqkvT,
    const float* __restrict__ Wo,   unsigned short* __restrict__ WoT,
    const float* __restrict__ W1,   unsigned short* __restrict__ W1T,
    const float* __restrict__ W2,   unsigned short* __restrict__ W2T,
    const float* __restrict__ x,    unsigned short* __restrict__ xb) {
  __shared__ float tile[32][33];
  const int b = blockIdx.x, tid = threadIdx.x;
  if (b >= 12288) {  // x f32 -> bf16, grid-stride
    for (int i = (b - 12288) * 256 + tid; i < 2097152; i += 2048 * 256) {
      float4 v = ((const float4*)x)[i];
      uint32_t lo = (uint32_t)f2b(v.x) | ((uint32_t)f2b(v.y) << 16);
      uint32_t hi = (uint32_t)f2b(v.z) | ((uint32_t)f2b(v.w) << 16);
      ((uint2*)xb)[i] = make_uint2(lo, hi);
    }
    return;
  }
  const float* W; unsigned short* WT; int K, N, jb, kb;
  if (b < 3072)       { W=Wqkv; WT=WqkvT; K=1024; N=3072; jb=b%96;          kb=b/96; }
  else if (b < 4096)  { W=Wo;   WT=WoT;   K=1024; N=1024; jb=(b-3072)%32;   kb=(b-3072)/32; }
  else if (b < 8192)  { W=W1;   WT=W1T;   K=1024; N=4096; jb=(b-4096)%128;  kb=(b-4096)/128; }
  else                { W=W2;   WT=W2T;   K=4096; N=1024; jb=(b-8192)%32;   kb=(b-8192)/32; }
  const int j0 = jb * 32, k0 = kb * 32;
  const int tx = tid & 31, ty = tid >> 5;
#pragma unroll
  for (int i = 0; i < 4; ++i)
    tile[ty + 8 * i][tx] = W[(size_t)(k0 + ty + 8 * i) * N + j0 + tx];
  __syncthreads();
#pragma unroll
  for (int i = 0; i < 4; ++i)
    WT[(size_t)(j0 + ty + 8 * i) * K + k0 + tx] = f2b(tile[tx][ty + 8 * i]);
}

// ---------------- GEMM: C(MxN) = A(MxK,bf16) * B^T(NxK,bf16) + bias ----------
template <bool SPLITK, bool OUTB, bool RELU>
__global__ __launch_bounds__(512, 2) void gemm2p_kernel(
    const unsigned short* __restrict__ A, const unsigned short* __restrict__ B,
    const float* __restrict__ bias, void* __restrict__ C,
    unsigned short* __restrict__ Cp1, unsigned short* __restrict__ Cp2,
    int M, int N, int Ks, int Kd, int nbn) {
  constexpr int HT = 128 * 64;            // elems per half-tile (16 KB)
  __shared__ unsigned short lds[8 * HT];  // 128 KB: [buf][A0,A1,B0,B1]

  const int tid  = threadIdx.x;
  const int lane = tid & 63, wave = tid >> 6;
  const int wm = wave >> 2, wn = wave & 3;  // 2 x 4 wave grid
  const int lr = lane & 15, lk = lane >> 4;
  const int x7 = lr & 7;

  // XCD-chunked swizzle, bn-fastest (all grids % 8 == 0)
  const int nwg = gridDim.x, cpx = nwg >> 3, id = blockIdx.x;
  const int wg = (id & 7) * cpx + (id >> 3);
  int bm, bn, sk;
  if (SPLITK) { bm = wg >> 3; bn = (wg & 7) >> 1; sk = wg & 1; }
  else        { bm = wg / nbn; bn = wg % nbn; sk = 0; }

  const unsigned short* Ab = A + (size_t)bm * 256 * Ks + (size_t)sk * Kd;
  const unsigned short* Bb = B + (size_t)bn * 256 * Ks + (size_t)sk * Kd;

  // staging: per half-tile, 2 issues of 512 lanes x 16B; source pre-swizzled
  const int srow = tid >> 3;                       // row 0..63 within issue
  const int scol = ((tid & 7) ^ (srow & 7)) * 8;   // swizzled col element
  const int ldst = wave * 8 * 64;                  // wave dest offset (elems)

  const int NT = Kd >> 6;  // >= 8 in all uses

  f32x4 acc[8][4] = {};
  bf16x8 aC[4][2], bH[2][2], bC[2][2];

#define SLOT_A(B_, H_) (((B_)*4 + (H_)) * HT)
#define SLOT_B(B_, H_) (((B_)*4 + 2 + (H_)) * HT)
#define STG_A(B_, H_, T_)                                                     \
  _Pragma("unroll") for (int i_ = 0; i_ < 2; ++i_)                            \
      gload_lds16(Ab + (size_t)((H_)*128 + i_ * 64 + srow) * Ks + (T_)*64 + scol, \
                  &lds[SLOT_A(B_, H_) + i_ * 64 * 64 + ldst])
#define STG_B(B_, H_, T_)                                                     \
  _Pragma("unroll") for (int i_ = 0; i_ < 2; ++i_)                            \
      gload_lds16(Bb + (size_t)((H_)*128 + i_ * 64 + srow) * Ks + (T_)*64 + scol, \
                  &lds[SLOT_B(B_, H_) + i_ * 64 * 64 + ldst])
// chunk-granular reads: one kk at a time (4 A-reads or 2 B-reads)
#define RDA_K(DST, B_, H_, KK)                                                \
  _Pragma("unroll") for (int mi_ = 0; mi_ < 4; ++mi_)                         \
      DST[mi_][KK] = *(const bf16x8*)&lds[SLOT_A(B_, H_) +                    \
          (wm * 64 + mi_ * 16 + lr) * 64 + (((KK)*4 + lk) ^ x7) * 8]
#define RDB_K(DST, B_, H_, KK)                                                \
  _Pragma("unroll") for (int ni_ = 0; ni_ < 2; ++ni_)                         \
      DST[ni_][KK] = *(const bf16x8*)&lds[SLOT_B(B_, H_) +                    \
          (wn * 32 + ni_ * 16 + lr) * 64 + (((KK)*4 + lk) ^ x7) * 8]
// 8-MFMA chunk: one (quadrant, kk)
#define MM8(AS, BS, MH, NH, KK)                                               \
  _Pragma("unroll") for (int mi_ = 0; mi_ < 4; ++mi_)                         \
    _Pragma("unroll") for (int ni_ = 0; ni_ < 2; ++ni_)                       \
      acc[(MH)*4 + mi_][(NH)*2 + ni_] =                                       \
          __builtin_amdgcn_mfma_f32_16x16x32_bf16(                            \
              AS[mi_][KK], BS[ni_][KK], acc[(MH)*4 + mi_][(NH)*2 + ni_], 0, 0, 0)
#define SB0() __builtin_amdgcn_sched_barrier(0)

  // ---- prologue: tile0 full {A0,B0,B1,A1} + tile1 {A0,B0} ----
  STG_A(0, 0, 0); STG_B(0, 0, 0); STG_B(0, 1, 0); STG_A(0, 1, 0);
  STG_A(1, 0, 1); STG_B(1, 0, 1);
  vmwait<4>();   // tile0 resident; tile1's {A0,B0} stay in flight
  barrier_sync();

  for (int t = 0; t < NT; ++t) {
    const int p = t & 1;
    const bool s1 = (t + 1 < NT), s2 = (t + 2 < NT);
    // ======== phase A: Q00 + Q01 ========
    // stage A1,B1(t+1) -> buf p^1 (slots last read @ phB(t-1)/phA(t-1))
    if (s1) { STG_A(p ^ 1, 1, t + 1); STG_B(p ^ 1, 1, t + 1); }
    // chunk-ordered reads: [A0k0, B0k0, A0k1, B0k1, B1k0, B1k1]
    RDA_K(aC, p, 0, 0); RDB_K(bH, p, 0, 0);
    RDA_K(aC, p, 0, 1); RDB_K(bH, p, 0, 1);
    RDB_K(bC, p, 1, 0); RDB_K(bC, p, 1, 1);
    barrier_sync();
    __builtin_amdgcn_s_setprio(1);
    MM8(aC, bH, 0, 0, 0); SB0();   // needs reads 1-6   -> lgkm(10)
    MM8(aC, bH, 0, 0, 1); SB0();   // needs reads 7-12  -> lgkm(4)
    MM8(aC, bC, 0, 1, 0); SB0();   // needs reads 13-14 -> lgkm(2)
    MM8(aC, bC, 0, 1, 1);          // needs all         -> lgkm(0)
    __builtin_amdgcn_s_setprio(0);
    barrier_sync();
    // ======== phase B: Q11 + Q10 ========
    // stage A0,B0(t+2) -> buf p (slots last read @ phase A above)
    if (s2) { STG_A(p, 0, t + 2); STG_B(p, 0, t + 2); }
    RDA_K(aC, p, 1, 0); RDA_K(aC, p, 1, 1);
    if (s2) vmwait<4>(); else if (s1) vmwait<0>();
    barrier_sync();
    __builtin_amdgcn_s_setprio(1);
    MM8(aC, bC, 1, 1, 0); SB0();   // needs A1k0 -> lgkm(4)
    MM8(aC, bH, 1, 0, 0); SB0();
    MM8(aC, bC, 1, 1, 1); SB0();   // needs all  -> lgkm(0)
    MM8(aC, bH, 1, 0, 1);
    __builtin_amdgcn_s_setprio(0);
    barrier_sync();
  }

#undef SB0
#undef MM8
#undef RDA_K
#undef RDB_K
#undef STG_A
#undef STG_B
#undef SLOT_A
#undef SLOT_B

  // ---- epilogue: C/D frag layout col = lane&15, row = (lane>>4)*4 + reg ----
  const int orow0 = bm * 256 + wm * 64;
  const int ocol0 = bn * 256 + wn * 32;
#pragma unroll
  for (int mh = 0; mh < 2; ++mh)
#pragma unroll
    for (int nh = 0; nh < 2; ++nh)
#pragma unroll
      for (int ni = 0; ni < 2; ++ni) {
        int col = ocol0 + nh * 128 + ni * 16 + lr;
        float bv = bias[col];
#pragma unroll
        for (int mi = 0; mi < 4; ++mi)
#pragma unroll
          for (int r = 0; r < 4; ++r) {
            int row = orow0 + mh * 128 + mi * 16 + lk * 4 + r;
            float val = acc[mh * 4 + mi][nh * 2 + ni][r];
            if (SPLITK) {
              unsigned short* dst = sk ? Cp2 : Cp1;
              dst[(size_t)row * N + col] = f2b(sk ? val : val + bv);
            } else {
              val += bv;
              if (RELU) val = fmaxf(val, 0.f);
              if (OUTB)
                ((unsigned short*)C)[(size_t)row * N + col] = f2b(val);
              else
                ((float*)C)[(size_t)row * N + col] = val;
            }
          }
      }
}

// ---------------- per-position head attention --------------------------------
__global__ __launch_bounds__(256) void attn_kernel(
    const unsigned short* __restrict__ qkv, const int* __restrict__ mask,
    unsigned short* __restrict__ outb) {
  __shared__ float sq[16][68], sk[16][68], sv[16][68];
  __shared__ float sp[16][17];
  const int pos = blockIdx.x;           // n*2048 + s
  const int n = pos >> 11, s = pos & 2047;
  const int tid = threadIdx.x;
  const unsigned short* row = qkv + (size_t)pos * 3072;
#pragma unroll
  for (int it = 0; it < 3; ++it) {
    uint2 raw = *(const uint2*)(row + it * 1024 + tid * 4);
    float f0 = b2f((unsigned short)(raw.x & 0xffffu));
    float f1 = b2f((unsigned short)(raw.x >> 16));
    float f2 = b2f((unsigned short)(raw.y & 0xffffu));
    float f3 = b2f((unsigned short)(raw.y >> 16));
    float(*dst)[68] = (it == 0) ? sq : (it == 1) ? sk : sv;
    int r = tid >> 4, d = (tid & 15) * 4;
    dst[r][d] = f0; dst[r][d + 1] = f1; dst[r][d + 2] = f2; dst[r][d + 3] = f3;
  }
  __syncthreads();
  {
    const int i = tid >> 4, j = tid & 15;
    float e = 0.f;
#pragma unroll
    for (int d = 0; d < 64; d += 4) {
      float4 qa = *(const float4*)&sq[i][d];
      float4 kb = *(const float4*)&sk[j][d];
      e += qa.x * kb.x + qa.y * kb.y + qa.z * kb.z + qa.w * kb.w;
    }
    if (mask[n * 16 + j] == 0) e = -1e20f;
    e *= 0.125f;  // 1/sqrt(64)
    float mx = e;
#pragma unroll
    for (int o = 8; o > 0; o >>= 1) mx = fmaxf(mx, __shfl_xor(mx, o, 16));
    float pe = __expf(e - mx);
    float sm = pe;
#pragma unroll
    for (int o = 8; o > 0; o >>= 1) sm += __shfl_xor(sm, o, 16);
    sp[i][j] = pe / sm;
  }
  __syncthreads();
  {
    const int w = tid >> 6, d = tid & 63;
    float o0 = 0, o1 = 0, o2 = 0, o3 = 0;
#pragma unroll
    for (int l = 0; l < 16; ++l) {
      float vv = sv[l][d];
      o0 += sp[w][l] * vv;      o1 += sp[w + 4][l] * vv;
      o2 += sp[w + 8][l] * vv;  o3 += sp[w + 12][l] * vv;
    }
    outb[(((size_t)n * 16 + w     ) * 2048 + s) * 64 + d] = f2b(o0);
    outb[(((size_t)n * 16 + w + 4 ) * 2048 + s) * 64 + d] = f2b(o1);
    outb[(((size_t)n * 16 + w + 8 ) * 2048 + s) * 64 + d] = f2b(o2);
    outb[(((size_t)n * 16 + w + 12) * 2048 + s) * 64 + d] = f2b(o3);
  }
}

// ---------------- LayerNorm(P1 + P2 + R) * g + beta --------------------------
// P1,P2: bf16 partials; R: residual (f32 if !RB16 else bf16).
template <bool RB16>
__global__ __launch_bounds__(256) void ln_kernel(
    const unsigned short* __restrict__ P1, const unsigned short* __restrict__ P2,
    const void* __restrict__ R,
    const float* __restrict__ g, const float* __restrict__ be,
    float* __restrict__ outf, unsigned short* __restrict__ outb) {
  const int row = blockIdx.x, tid = threadIdx.x;
  const size_t base = (size_t)row * 1024 + tid * 4;
  uint2 p = *(const uint2*)(P1 + base);
  uint2 q = *(const uint2*)(P2 + base);
  float x0 = b2f((unsigned short)(p.x & 0xffffu)) + b2f((unsigned short)(q.x & 0xffffu));
  float x1 = b2f((unsigned short)(p.x >> 16))     + b2f((unsigned short)(q.x >> 16));
  float x2 = b2f((unsigned short)(p.y & 0xffffu)) + b2f((unsigned short)(q.y & 0xffffu));
  float x3 = b2f((unsigned short)(p.y >> 16))     + b2f((unsigned short)(q.y >> 16));
  if (RB16) {
    uint2 r = *(const uint2*)((const unsigned short*)R + base);
    x0 += b2f((unsigned short)(r.x & 0xffffu));
    x1 += b2f((unsigned short)(r.x >> 16));
    x2 += b2f((unsigned short)(r.y & 0xffffu));
    x3 += b2f((unsigned short)(r.y >> 16));
  } else {
    float4 r = *(const float4*)((const float*)R + base);
    x0 += r.x; x1 += r.y; x2 += r.z; x3 += r.w;
  }
  float s = x0 + x1 + x2 + x3;
#pragma unroll
  for (int o = 32; o > 0; o >>= 1) s += __shfl_xor(s, o);
  __shared__ float red[4];
  const int lane = tid & 63, wv = tid >> 6;
  if (lane == 0) red[wv] = s;
  __syncthreads();
  float mean = (red[0] + red[1] + red[2] + red[3]) * (1.f / 1024.f);
  float d0 = x0 - mean, d1 = x1 - mean, d2 = x2 - mean, d3 = x3 - mean;
  float qd = d0 * d0 + d1 * d1 + d2 * d2 + d3 * d3;
#pragma unroll
  for (int o = 32; o > 0; o >>= 1) qd += __shfl_xor(qd, o);
  __syncthreads();
  if (lane == 0) red[wv] = qd;
  __syncthreads();
  float var = (red[0] + red[1] + red[2] + red[3]) * (1.f / 1024.f);
  float rs = rsqrtf(var + 1e-5f);
  const int col = tid * 4;
  float4 gv = *(const float4*)(g + col);
  float4 bv = *(const float4*)(be + col);
  float y0 = d0 * rs * gv.x + bv.x;
  float y1 = d1 * rs * gv.y + bv.y;
  float y2 = d2 * rs * gv.z + bv.z;
  float y3 = d3 * rs * gv.w + bv.w;
  if (outf) *(float4*)(outf + base) = make_float4(y0, y1, y2, y3);
  if (outb) {
    uint32_t lo = (uint32_t)f2b(y0) | ((uint32_t)f2b(y1) << 16);
    uint32_t hi = (uint32_t)f2b(y2) | ((uint32_t)f2b(y3) << 16);
    *(uint2*)(outb + base) = make_uint2(lo, hi);
  }
}

// ---------------- launch ------------------------------------------------------
extern "C" void kernel_launch(void* const* d_in, const int* in_sizes, int n_in,
                              void* d_out, int out_size, void* d_ws,
                              size_t ws_size, hipStream_t stream) {
  (void)in_sizes; (void)n_in; (void)out_size; (void)ws_size;
  const float* x     = (const float*)d_in[0];
  const float* Wqkv  = (const float*)d_in[1];
  const float* bqkv  = (const float*)d_in[2];
  const float* Wo    = (const float*)d_in[3];
  const float* bo    = (const float*)d_in[4];
  const float* g1    = (const float*)d_in[5];
  const float* beta1 = (const float*)d_in[6];
  const float* W1    = (const float*)d_in[7];
  const float* bf1   = (const float*)d_in[8];
  const float* W2    = (const float*)d_in[9];
  const float* bf2   = (const float*)d_in[10];
  const float* g2    = (const float*)d_in[11];
  const float* beta2 = (const float*)d_in[12];
  const int*   mask  = (const int*)d_in[13];
  float* out = (float*)d_out;

  char* ws = (char*)d_ws;
  unsigned short* WqkvT = (unsigned short*)(ws + 0);          //  6 MB
  unsigned short* WoT   = (unsigned short*)(ws + 6291456);    //  2 MB
  unsigned short* W1T   = (unsigned short*)(ws + 8388608);    //  8 MB
  unsigned short* W2T   = (unsigned short*)(ws + 16777216);   //  8 MB
  unsigned short* xb    = (unsigned short*)(ws + 25165824);   // 16 MB
  unsigned short* h_b   = (unsigned short*)(ws + 41943040);   // 16 MB
  unsigned short* aop1  = (unsigned short*)(ws + 58720256);   // 16 MB
  unsigned short* aop2  = (unsigned short*)(ws + 75497472);   // 16 MB
  unsigned short* qkvb  = (unsigned short*)(ws + 92274688);   // 48 MB
  unsigned short* aob   = (unsigned short*)(ws + 142606336);  // 16 MB
  unsigned short* ff1   = qkvb;   // 64 MB spanning qkvb+aob (dead by then)
  unsigned short* ffp1  = aop1;   // dead after LN1
  unsigned short* ffp2  = aop2;   // dead after LN1

  prep_kernel<<<14336, 256, 0, stream>>>(Wqkv, WqkvT, Wo, WoT, W1, W1T, W2, W2T, x, xb);

  gemm2p_kernel<false, true, false><<<dim3(384), 512, 0, stream>>>(
      xb, WqkvT, bqkv, qkvb, nullptr, nullptr, 8192, 3072, 1024, 1024, 12);
  attn_kernel<<<8192, 256, 0, stream>>>(qkvb, mask, aob);
  gemm2p_kernel<true, false, false><<<dim3(256), 512, 0, stream>>>(
      aob, WoT, bo, nullptr, aop1, aop2, 8192, 1024, 1024, 512, 4);
  ln_kernel<false><<<8192, 256, 0, stream>>>(aop1, aop2, x, g1, beta1, nullptr, h_b);
  gemm2p_kernel<false, true, true><<<dim3(512), 512, 0, stream>>>(
      h_b, W1T, bf1, ff1, nullptr, nullptr, 8192, 4096, 1024, 1024, 16);
  gemm2p_kernel<true, false, false><<<dim3(256), 512, 0, stream>>>(
      ff1, W2T, bf2, nullptr, ffp1, ffp2, 8192, 1024, 4096, 2048, 4);
  ln_kernel<true><<<8192, 256, 0, stream>>>(ffp1, ffp2, h_b, g2, beta2, out, nullptr);
}

// Round 11
// 291.047 us; speedup vs baseline: 1.0294x; 1.0294x over previous
//
#include <hip/hip_runtime.h>
#include <cstdint>
#include <cstddef>

// EncoderLayer: x(4,2048,1024) f32.
//   prep (1 kernel): W* (KxN f32) -> W*T (NxK bf16); x -> xb bf16
//   G1: qkv_b  = xb @ WqkvT + bqkv              (8192x3072, bf16)  grid 384
//   attn: per-position 16x16 head attention, out (N,H,S,hd) = scrambled reshape
//   G2: ao = aob @ WoT + bo      SPLIT-K=2 -> 2x bf16 partials      grid 256
//   LN1: h_b = LN(p1 + p2 + x)  (bf16 only)
//   G3: ff1 = relu(h_b @ W1T + bf1)             (8192x4096, bf16)  grid 512
//   G4: ff2 = ff1 @ W2T + bf2    SPLIT-K=2 -> 2x bf16 partials      grid 256
//   LN2: out = LN(q1 + q2 + h_b)                (f32 -> d_out)
//
// GEMM v9 "cross-cluster read-ahead" (R10 postmortem: all same-phase-consume
// structures serialize DS+MFMA at ~5660 cy/K-tile). Per K-tile: 8 clusters
// of 8 MFMA, ONE barrier each. Every ds_read is issued TWO clusters before
// its consuming MFMA -> LDS service hides under the intervening MFMA via
// compiler-derived counted lgkmcnt (the m201 "lgkmcnt(8)" mechanism).
// Rotation (R6's register plan, 124 VGPR, fits): Ax,Ay (4 frags ea) +
// Bp,Bq,Br (2 frags ea). Cluster order (mh,nh) x kk gray-code:
//   C1(0,0)k0 C2(0,1)k0 C3(1,1)k0 C4(1,0)k0 C5(1,0)k1 C6(1,1)k1 C7(0,1)k1 C8(0,0)k1
// Reads: C1:Ay<-A1k0(t) C3:Ax<-A1k1(t),Br<-B0k1(t) C4:Bq<-B1k1(t)
//        C5:Ay<-A0k1(t) C7:Ax<-A0k0(t+1),Bp<-B0k0(t+1) C8:Bq<-B1k0(t+1)
// Stages: C1:A0(t+1) C2:B0(t+1) C7:A1(t+2) C8:B1(t+2).
// ONE vmcnt(0) per tile at end-C6 (newest stage is 4 clusters old, ~1500cy
// >= 900 HBM -> no stall) guards all t+1 reads CU-wide (wait->barrier->read).
// Barriers are raw s_barrier (no "memory" clobber -> no forced drain).

using f32x4  = __attribute__((ext_vector_type(4))) float;
using bf16x8 = __attribute__((ext_vector_type(8))) __bf16;

__device__ __forceinline__ unsigned short f2b(float f) {
  union { float f; uint32_t u; } v; v.f = f;
  uint32_t r = v.u + 0x7FFFu + ((v.u >> 16) & 1u);  // RNE
  return (unsigned short)(r >> 16);
}
__device__ __forceinline__ float b2f(unsigned short u) {
  union { uint32_t u; float f; } v; v.u = ((uint32_t)u) << 16;
  return v.f;
}

__device__ __forceinline__ void gload_lds16(const unsigned short* g,
                                            unsigned short* l) {
  __builtin_amdgcn_global_load_lds(
      (const __attribute__((address_space(1))) unsigned int*)g,
      (__attribute__((address_space(3))) unsigned int*)l, 16, 0, 0);
}

__device__ __forceinline__ void barrier_sync() {
  __builtin_amdgcn_sched_barrier(0);
  __builtin_amdgcn_s_barrier();
  __builtin_amdgcn_sched_barrier(0);
}
template <int N>
__device__ __forceinline__ void vmwait() {
  __builtin_amdgcn_sched_barrier(0);
  if constexpr (N == 0) asm volatile("s_waitcnt vmcnt(0)");
  if constexpr (N == 4) asm volatile("s_waitcnt vmcnt(4)");
  __builtin_amdgcn_sched_barrier(0);
}

// ---------------- fused prep: 4 weight transposes + x cvt --------------------
__global__ __launch_bounds__(256) void prep_kernel(
    const float* __restrict__ Wqkv, unsigned short* __restrict__ WqkvT,
    const float* __restrict__ Wo,   unsigned short* __restrict__ WoT,
    const float* __restrict__ W1,   unsigned short* __restrict__ W1T,
    const float* __restrict__ W2,   unsigned short* __restrict__ W2T,
    const float* __restrict__ x,    unsigned short* __restrict__ xb) {
  __shared__ float tile[32][33];
  const int b = blockIdx.x, tid = threadIdx.x;
  if (b >= 12288) {  // x f32 -> bf16, grid-stride
    for (int i = (b - 12288) * 256 + tid; i < 2097152; i += 2048 * 256) {
      float4 v = ((const float4*)x)[i];
      uint32_t lo = (uint32_t)f2b(v.x) | ((uint32_t)f2b(v.y) << 16);
      uint32_t hi = (uint32_t)f2b(v.z) | ((uint32_t)f2b(v.w) << 16);
      ((uint2*)xb)[i] = make_uint2(lo, hi);
    }
    return;
  }
  const float* W; unsigned short* WT; int K, N, jb, kb;
  if (b < 3072)       { W=Wqkv; WT=WqkvT; K=1024; N=3072; jb=b%96;          kb=b/96; }
  else if (b < 4096)  { W=Wo;   WT=WoT;   K=1024; N=1024; jb=(b-3072)%32;   kb=(b-3072)/32; }
  else if (b < 8192)  { W=W1;   WT=W1T;   K=1024; N=4096; jb=(b-4096)%128;  kb=(b-4096)/128; }
  else                { W=W2;   WT=W2T;   K=4096; N=1024; jb=(b-8192)%32;   kb=(b-8192)/32; }
  const int j0 = jb * 32, k0 = kb * 32;
  const int tx = tid & 31, ty = tid >> 5;
#pragma unroll
  for (int i = 0; i < 4; ++i)
    tile[ty + 8 * i][tx] = W[(size_t)(k0 + ty + 8 * i) * N + j0 + tx];
  __syncthreads();
#pragma unroll
  for (int i = 0; i < 4; ++i)
    WT[(size_t)(j0 + ty + 8 * i) * K + k0 + tx] = f2b(tile[tx][ty + 8 * i]);
}

// ---------------- GEMM: C(MxN) = A(MxK,bf16) * B^T(NxK,bf16) + bias ----------
template <bool SPLITK, bool OUTB, bool RELU>
__global__ __launch_bounds__(512, 2) void gemmr_kernel(
    const unsigned short* __restrict__ A, const unsigned short* __restrict__ B,
    const float* __restrict__ bias, void* __restrict__ C,
    unsigned short* __restrict__ Cp1, unsigned short* __restrict__ Cp2,
    int M, int N, int Ks, int Kd, int nbn) {
  constexpr int HT = 128 * 64;            // elems per half-tile (16 KB)
  __shared__ unsigned short lds[8 * HT];  // 128 KB: [buf][A0,A1,B0,B1]

  const int tid  = threadIdx.x;
  const int lane = tid & 63, wave = tid >> 6;
  const int wm = wave >> 2, wn = wave & 3;  // 2 x 4 wave grid
  const int lr = lane & 15, lk = lane >> 4;
  const int x7 = lr & 7;

  // XCD-chunked swizzle, bn-fastest (all grids % 8 == 0)
  const int nwg = gridDim.x, cpx = nwg >> 3, id = blockIdx.x;
  const int wg = (id & 7) * cpx + (id >> 3);
  int bm, bn, sk;
  if (SPLITK) { bm = wg >> 3; bn = (wg & 7) >> 1; sk = wg & 1; }
  else        { bm = wg / nbn; bn = wg % nbn; sk = 0; }

  const unsigned short* Ab = A + (size_t)bm * 256 * Ks + (size_t)sk * Kd;
  const unsigned short* Bb = B + (size_t)bn * 256 * Ks + (size_t)sk * Kd;

  // staging: per half-tile, 2 issues of 512 lanes x 16B; source pre-swizzled
  const int srow = tid >> 3;                       // row 0..63 within issue
  const int scol = ((tid & 7) ^ (srow & 7)) * 8;   // swizzled col element
  const int ldst = wave * 8 * 64;                  // wave dest offset (elems)

  const int NT = Kd >> 6;  // >= 8 in all uses

  f32x4 acc[8][4] = {};
  bf16x8 aX[4], aY[4], bP[2], bQ[2], bR[2];

#define SLOT_A(B_, H_) (((B_)*4 + (H_)) * HT)
#define SLOT_B(B_, H_) (((B_)*4 + 2 + (H_)) * HT)
#define STG_A(B_, H_, T_)                                                     \
  _Pragma("unroll") for (int i_ = 0; i_ < 2; ++i_)                            \
      gload_lds16(Ab + (size_t)((H_)*128 + i_ * 64 + srow) * Ks + (T_)*64 + scol, \
                  &lds[SLOT_A(B_, H_) + i_ * 64 * 64 + ldst])
#define STG_B(B_, H_, T_)                                                     \
  _Pragma("unroll") for (int i_ = 0; i_ < 2; ++i_)                            \
      gload_lds16(Bb + (size_t)((H_)*128 + i_ * 64 + srow) * Ks + (T_)*64 + scol, \
                  &lds[SLOT_B(B_, H_) + i_ * 64 * 64 + ldst])
// frag reads: A-set = 4x b128 (one mh, one kk); B-set = 2x b128 (one nh, one kk)
#define RD_A(DST, B_, H_, KK)                                                 \
  _Pragma("unroll") for (int mi_ = 0; mi_ < 4; ++mi_)                         \
      DST[mi_] = *(const bf16x8*)&lds[SLOT_A(B_, H_) +                        \
          (wm * 64 + mi_ * 16 + lr) * 64 + (((KK)*4 + lk) ^ x7) * 8]
#define RD_B(DST, B_, H_, KK)                                                 \
  _Pragma("unroll") for (int ni_ = 0; ni_ < 2; ++ni_)                         \
      DST[ni_] = *(const bf16x8*)&lds[SLOT_B(B_, H_) +                        \
          (wn * 32 + ni_ * 16 + lr) * 64 + (((KK)*4 + lk) ^ x7) * 8]
#define MM8(AS, BS, MH, NH)                                                   \
  do {                                                                        \
    __builtin_amdgcn_s_setprio(1);                                            \
    _Pragma("unroll") for (int mi_ = 0; mi_ < 4; ++mi_)                       \
      _Pragma("unroll") for (int ni_ = 0; ni_ < 2; ++ni_)                     \
        acc[(MH)*4 + mi_][(NH)*2 + ni_] =                                     \
            __builtin_amdgcn_mfma_f32_16x16x32_bf16(                          \
                AS[mi_], BS[ni_], acc[(MH)*4 + mi_][(NH)*2 + ni_], 0, 0, 0);  \
    __builtin_amdgcn_s_setprio(0);                                            \
  } while (0)

  // ---- prologue: stage A0,B0,A1,B1(0) + A1,B1(1); preload Ax,Bp,Bq ----
  STG_A(0, 0, 0); STG_B(0, 0, 0); STG_A(0, 1, 0); STG_B(0, 1, 0);
  STG_A(1, 1, 1); STG_B(1, 1, 1);
  vmwait<4>();   // tile0 resident; A1(1),B1(1) stay in flight
  barrier_sync();
  RD_A(aX, 0, 0, 0);   // A0k0(0) -> C1,C2
  RD_B(bP, 0, 0, 0);   // B0k0(0) -> C1,C4
  RD_B(bQ, 0, 1, 0);   // B1k0(0) -> C2,C3

  for (int t = 0; t < NT; ++t) {
    const int p = t & 1;
    const bool s1 = (t + 1 < NT), s2 = (t + 2 < NT);
    // C1 (0,0)k0: read Ay<-A1k0(t); stage A0(t+1)
    RD_A(aY, p, 1, 0);
    if (s1) STG_A(p ^ 1, 0, t + 1);
    barrier_sync();
    MM8(aX, bP, 0, 0);
    // C2 (0,1)k0: stage B0(t+1)
    if (s1) STG_B(p ^ 1, 0, t + 1);
    barrier_sync();
    MM8(aX, bQ, 0, 1);
    // C3 (1,1)k0: read Ax<-A1k1(t), Br<-B0k1(t)
    RD_A(aX, p, 1, 1);
    RD_B(bR, p, 0, 1);
    barrier_sync();
    MM8(aY, bQ, 1, 1);
    // C4 (1,0)k0: read Bq<-B1k1(t)
    RD_B(bQ, p, 1, 1);
    barrier_sync();
    MM8(aY, bP, 1, 0);
    // C5 (1,0)k1: read Ay<-A0k1(t)
    RD_A(aY, p, 0, 1);
    barrier_sync();
    MM8(aX, bR, 1, 0);
    // C6 (1,1)k1: drain stages (newest is 4 clusters old; guards C7/C8 reads)
    vmwait<0>();
    barrier_sync();
    MM8(aX, bQ, 1, 1);
    // C7 (0,1)k1: read Ax<-A0k0(t+1), Bp<-B0k0(t+1); stage A1(t+2)
    if (s1) { RD_A(aX, p ^ 1, 0, 0); RD_B(bP, p ^ 1, 0, 0); }
    if (s2) STG_A(p, 1, t + 2);
    barrier_sync();
    MM8(aY, bQ, 0, 1);
    // C8 (0,0)k1: read Bq<-B1k0(t+1); stage B1(t+2)
    if (s1) RD_B(bQ, p ^ 1, 1, 0);
    if (s2) STG_B(p, 1, t + 2);
    barrier_sync();
    MM8(aY, bR, 0, 0);
  }

#undef MM8
#undef RD_A
#undef RD_B
#undef STG_A
#undef STG_B
#undef SLOT_A
#undef SLOT_B

  // ---- epilogue: C/D frag layout col = lane&15, row = (lane>>4)*4 + reg ----
  const int orow0 = bm * 256 + wm * 64;
  const int ocol0 = bn * 256 + wn * 32;
#pragma unroll
  for (int mh = 0; mh < 2; ++mh)
#pragma unroll
    for (int nh = 0; nh < 2; ++nh)
#pragma unroll
      for (int ni = 0; ni < 2; ++ni) {
        int col = ocol0 + nh * 128 + ni * 16 + lr;
        float bv = bias[col];
#pragma unroll
        for (int mi = 0; mi < 4; ++mi)
#pragma unroll
          for (int r = 0; r < 4; ++r) {
            int row = orow0 + mh * 128 + mi * 16 + lk * 4 + r;
            float val = acc[mh * 4 + mi][nh * 2 + ni][r];
            if (SPLITK) {
              unsigned short* dst = sk ? Cp2 : Cp1;
              dst[(size_t)row * N + col] = f2b(sk ? val : val + bv);
            } else {
              val += bv;
              if (RELU) val = fmaxf(val, 0.f);
              if (OUTB)
                ((unsigned short*)C)[(size_t)row * N + col] = f2b(val);
              else
                ((float*)C)[(size_t)row * N + col] = val;
            }
          }
      }
}

// ---------------- per-position head attention --------------------------------
__global__ __launch_bounds__(256) void attn_kernel(
    const unsigned short* __restrict__ qkv, const int* __restrict__ mask,
    unsigned short* __restrict__ outb) {
  __shared__ float sq[16][68], sk[16][68], sv[16][68];
  __shared__ float sp[16][17];
  const int pos = blockIdx.x;           // n*2048 + s
  const int n = pos >> 11, s = pos & 2047;
  const int tid = threadIdx.x;
  const unsigned short* row = qkv + (size_t)pos * 3072;
#pragma unroll
  for (int it = 0; it < 3; ++it) {
    uint2 raw = *(const uint2*)(row + it * 1024 + tid * 4);
    float f0 = b2f((unsigned short)(raw.x & 0xffffu));
    float f1 = b2f((unsigned short)(raw.x >> 16));
    float f2 = b2f((unsigned short)(raw.y & 0xffffu));
    float f3 = b2f((unsigned short)(raw.y >> 16));
    float(*dst)[68] = (it == 0) ? sq : (it == 1) ? sk : sv;
    int r = tid >> 4, d = (tid & 15) * 4;
    dst[r][d] = f0; dst[r][d + 1] = f1; dst[r][d + 2] = f2; dst[r][d + 3] = f3;
  }
  __syncthreads();
  {
    const int i = tid >> 4, j = tid & 15;
    float e = 0.f;
#pragma unroll
    for (int d = 0; d < 64; d += 4) {
      float4 qa = *(const float4*)&sq[i][d];
      float4 kb = *(const float4*)&sk[j][d];
      e += qa.x * kb.x + qa.y * kb.y + qa.z * kb.z + qa.w * kb.w;
    }
    if (mask[n * 16 + j] == 0) e = -1e20f;
    e *= 0.125f;  // 1/sqrt(64)
    float mx = e;
#pragma unroll
    for (int o = 8; o > 0; o >>= 1) mx = fmaxf(mx, __shfl_xor(mx, o, 16));
    float pe = __expf(e - mx);
    float sm = pe;
#pragma unroll
    for (int o = 8; o > 0; o >>= 1) sm += __shfl_xor(sm, o, 16);
    sp[i][j] = pe / sm;
  }
  __syncthreads();
  {
    const int w = tid >> 6, d = tid & 63;
    float o0 = 0, o1 = 0, o2 = 0, o3 = 0;
#pragma unroll
    for (int l = 0; l < 16; ++l) {
      float vv = sv[l][d];
      o0 += sp[w][l] * vv;      o1 += sp[w + 4][l] * vv;
      o2 += sp[w + 8][l] * vv;  o3 += sp[w + 12][l] * vv;
    }
    outb[(((size_t)n * 16 + w     ) * 2048 + s) * 64 + d] = f2b(o0);
    outb[(((size_t)n * 16 + w + 4 ) * 2048 + s) * 64 + d] = f2b(o1);
    outb[(((size_t)n * 16 + w + 8 ) * 2048 + s) * 64 + d] = f2b(o2);
    outb[(((size_t)n * 16 + w + 12) * 2048 + s) * 64 + d] = f2b(o3);
  }
}

// ---------------- LayerNorm(P1 + P2 + R) * g + beta --------------------------
// P1,P2: bf16 partials; R: residual (f32 if !RB16 else bf16).
template <bool RB16>
__global__ __launch_bounds__(256) void ln_kernel(
    const unsigned short* __restrict__ P1, const unsigned short* __restrict__ P2,
    const void* __restrict__ R,
    const float* __restrict__ g, const float* __restrict__ be,
    float* __restrict__ outf, unsigned short* __restrict__ outb) {
  const int row = blockIdx.x, tid = threadIdx.x;
  const size_t base = (size_t)row * 1024 + tid * 4;
  uint2 p = *(const uint2*)(P1 + base);
  uint2 q = *(const uint2*)(P2 + base);
  float x0 = b2f((unsigned short)(p.x & 0xffffu)) + b2f((unsigned short)(q.x & 0xffffu));
  float x1 = b2f((unsigned short)(p.x >> 16))     + b2f((unsigned short)(q.x >> 16));
  float x2 = b2f((unsigned short)(p.y & 0xffffu)) + b2f((unsigned short)(q.y & 0xffffu));
  float x3 = b2f((unsigned short)(p.y >> 16))     + b2f((unsigned short)(q.y >> 16));
  if (RB16) {
    uint2 r = *(const uint2*)((const unsigned short*)R + base);
    x0 += b2f((unsigned short)(r.x & 0xffffu));
    x1 += b2f((unsigned short)(r.x >> 16));
    x2 += b2f((unsigned short)(r.y & 0xffffu));
    x3 += b2f((unsigned short)(r.y >> 16));
  } else {
    float4 r = *(const float4*)((const float*)R + base);
    x0 += r.x; x1 += r.y; x2 += r.z; x3 += r.w;
  }
  float s = x0 + x1 + x2 + x3;
#pragma unroll
  for (int o = 32; o > 0; o >>= 1) s += __shfl_xor(s, o);
  __shared__ float red[4];
  const int lane = tid & 63, wv = tid >> 6;
  if (lane == 0) red[wv] = s;
  __syncthreads();
  float mean = (red[0] + red[1] + red[2] + red[3]) * (1.f / 1024.f);
  float d0 = x0 - mean, d1 = x1 - mean, d2 = x2 - mean, d3 = x3 - mean;
  float qd = d0 * d0 + d1 * d1 + d2 * d2 + d3 * d3;
#pragma unroll
  for (int o = 32; o > 0; o >>= 1) qd += __shfl_xor(qd, o);
  __syncthreads();
  if (lane == 0) red[wv] = qd;
  __syncthreads();
  float var = (red[0] + red[1] + red[2] + red[3]) * (1.f / 1024.f);
  float rs = rsqrtf(var + 1e-5f);
  const int col = tid * 4;
  float4 gv = *(const float4*)(g + col);
  float4 bv = *(const float4*)(be + col);
  float y0 = d0 * rs * gv.x + bv.x;
  float y1 = d1 * rs * gv.y + bv.y;
  float y2 = d2 * rs * gv.z + bv.z;
  float y3 = d3 * rs * gv.w + bv.w;
  if (outf) *(float4*)(outf + base) = make_float4(y0, y1, y2, y3);
  if (outb) {
    uint32_t lo = (uint32_t)f2b(y0) | ((uint32_t)f2b(y1) << 16);
    uint32_t hi = (uint32_t)f2b(y2) | ((uint32_t)f2b(y3) << 16);
    *(uint2*)(outb + base) = make_uint2(lo, hi);
  }
}

// ---------------- launch ------------------------------------------------------
extern "C" void kernel_launch(void* const* d_in, const int* in_sizes, int n_in,
                              void* d_out, int out_size, void* d_ws,
                              size_t ws_size, hipStream_t stream) {
  (void)in_sizes; (void)n_in; (void)out_size; (void)ws_size;
  const float* x     = (const float*)d_in[0];
  const float* Wqkv  = (const float*)d_in[1];
  const float* bqkv  = (const float*)d_in[2];
  const float* Wo    = (const float*)d_in[3];
  const float* bo    = (const float*)d_in[4];
  const float* g1    = (const float*)d_in[5];
  const float* beta1 = (const float*)d_in[6];
  const float* W1    = (const float*)d_in[7];
  const float* bf1   = (const float*)d_in[8];
  const float* W2    = (const float*)d_in[9];
  const float* bf2   = (const float*)d_in[10];
  const float* g2    = (const float*)d_in[11];
  const float* beta2 = (const float*)d_in[12];
  const int*   mask  = (const int*)d_in[13];
  float* out = (float*)d_out;

  char* ws = (char*)d_ws;
  unsigned short* WqkvT = (unsigned short*)(ws + 0);          //  6 MB
  unsigned short* WoT   = (unsigned short*)(ws + 6291456);    //  2 MB
  unsigned short* W1T   = (unsigned short*)(ws + 8388608);    //  8 MB
  unsigned short* W2T   = (unsigned short*)(ws + 16777216);   //  8 MB
  unsigned short* xb    = (unsigned short*)(ws + 25165824);   // 16 MB
  unsigned short* h_b   = (unsigned short*)(ws + 41943040);   // 16 MB
  unsigned short* aop1  = (unsigned short*)(ws + 58720256);   // 16 MB
  unsigned short* aop2  = (unsigned short*)(ws + 75497472);   // 16 MB
  unsigned short* qkvb  = (unsigned short*)(ws + 92274688);   // 48 MB
  unsigned short* aob   = (unsigned short*)(ws + 142606336);  // 16 MB
  unsigned short* ff1   = qkvb;   // 64 MB spanning qkvb+aob (dead by then)
  unsigned short* ffp1  = aop1;   // dead after LN1
  unsigned short* ffp2  = aop2;   // dead after LN1

  prep_kernel<<<14336, 256, 0, stream>>>(Wqkv, WqkvT, Wo, WoT, W1, W1T, W2, W2T, x, xb);

  gemmr_kernel<false, true, false><<<dim3(384), 512, 0, stream>>>(
      xb, WqkvT, bqkv, qkvb, nullptr, nullptr, 8192, 3072, 1024, 1024, 12);
  attn_kernel<<<8192, 256, 0, stream>>>(qkvb, mask, aob);
  gemmr_kernel<true, false, false><<<dim3(256), 512, 0, stream>>>(
      aob, WoT, bo, nullptr, aop1, aop2, 8192, 1024, 1024, 512, 4);
  ln_kernel<false><<<8192, 256, 0, stream>>>(aop1, aop2, x, g1, beta1, nullptr, h_b);
  gemmr_kernel<false, true, true><<<dim3(512), 512, 0, stream>>>(
      h_b, W1T, bf1, ff1, nullptr, nullptr, 8192, 4096, 1024, 1024, 16);
  gemmr_kernel<true, false, false><<<dim3(256), 512, 0, stream>>>(
      ff1, W2T, bf2, nullptr, ffp1, ffp2, 8192, 1024, 4096, 2048, 4);
  ln_kernel<true><<<8192, 256, 0, stream>>>(ffp1, ffp2, h_b, g2, beta2, out, nullptr);
}